// Round 9
// baseline (763.573 us; speedup 1.0000x reference)
//
#include <hip/hip_runtime.h>
#include <hip/hip_bf16.h>

#define F 64
#define SLOPE 0.2f
#define NB_SHIFT 7     // 128 nodes per coarse bucket
#define BMASK 127
#define BATCH 4096     // edges per gat_bin block
#define ACC_STRIDE 68  // 128-node accumulator stride (bank-friendly)

__device__ inline unsigned short f2bf(float f) {
    unsigned u = __float_as_uint(f);
    unsigned r = (u + 0x7FFFu + ((u >> 16) & 1u)) >> 16;
    return (unsigned short)r;
}

// ---------------- Kernel 1: h(bf16) = X @ W + fused s1/s2 -------------------
__global__ __launch_bounds__(256) void gat_gemm(
    const float* __restrict__ X, const float* __restrict__ W,
    const float* __restrict__ a, unsigned short* __restrict__ hb,
    float* __restrict__ s1, float* __restrict__ s2, int N) {
    __shared__ __align__(16) char smem[51200];
    float* XsT = (float*)smem;              // 64*132*4 = 33792 B
    float* Wsm = (float*)(smem + 33792);    // 64*68*4  = 17408 B

    const int tid = threadIdx.x;
    const int base = blockIdx.x * 128;

#pragma unroll
    for (int l = 0; l < 8; ++l) {
        int flat = l * 256 + tid;
        int rr = flat >> 4;
        int qc = flat & 15;
        float4 v = make_float4(0.f, 0.f, 0.f, 0.f);
        if (base + rr < N) v = *(const float4*)&X[(size_t)(base + rr) * F + qc * 4];
        XsT[(qc * 4 + 0) * 132 + rr] = v.x;
        XsT[(qc * 4 + 1) * 132 + rr] = v.y;
        XsT[(qc * 4 + 2) * 132 + rr] = v.z;
        XsT[(qc * 4 + 3) * 132 + rr] = v.w;
    }
#pragma unroll
    for (int l = 0; l < 4; ++l) {
        int flat = l * 256 + tid;
        int k = flat >> 4;
        int qc = flat & 15;
        float4 v = *(const float4*)&W[k * F + qc * 4];
        *(float4*)&Wsm[k * 68 + qc * 4] = v;
    }
    __syncthreads();

    const int r0 = (tid >> 4) * 8;
    const int c0 = (tid & 15) * 4;

    float4 acc[8];
#pragma unroll
    for (int i = 0; i < 8; ++i) acc[i] = make_float4(0.f, 0.f, 0.f, 0.f);

#pragma unroll 8
    for (int k = 0; k < F; ++k) {
        float4 xa = *(float4*)&XsT[k * 132 + r0];
        float4 xb = *(float4*)&XsT[k * 132 + r0 + 4];
        float4 wv = *(float4*)&Wsm[k * 68 + c0];
        float xs[8] = {xa.x, xa.y, xa.z, xa.w, xb.x, xb.y, xb.z, xb.w};
#pragma unroll
        for (int i = 0; i < 8; ++i) {
            acc[i].x = fmaf(xs[i], wv.x, acc[i].x);
            acc[i].y = fmaf(xs[i], wv.y, acc[i].y);
            acc[i].z = fmaf(xs[i], wv.z, acc[i].z);
            acc[i].w = fmaf(xs[i], wv.w, acc[i].w);
        }
    }

#pragma unroll
    for (int i = 0; i < 8; ++i) {
        int r = base + r0 + i;
        if (r < N) {
            ushort4 hv;
            hv.x = f2bf(acc[i].x);
            hv.y = f2bf(acc[i].y);
            hv.z = f2bf(acc[i].z);
            hv.w = f2bf(acc[i].w);
            *(ushort4*)&hb[(size_t)r * F + c0] = hv;
        }
    }

    float4 a1 = *(const float4*)&a[c0];
    float4 a2 = *(const float4*)&a[F + c0];
    __syncthreads();
    float2* red = (float2*)Wsm;            // [16][128] float2
    const int cg = tid & 15;
#pragma unroll
    for (int i = 0; i < 8; ++i) {
        float p = acc[i].x * a1.x + acc[i].y * a1.y + acc[i].z * a1.z + acc[i].w * a1.w;
        float q = acc[i].x * a2.x + acc[i].y * a2.y + acc[i].z * a2.z + acc[i].w * a2.w;
        red[cg * 128 + r0 + i] = make_float2(p, q);
    }
    __syncthreads();
    if (tid < 128) {
        float p = 0.f, q = 0.f;
#pragma unroll
        for (int g = 0; g < 16; ++g) {
            float2 t = red[g * 128 + tid];
            p += t.x;
            q += t.y;
        }
        int r = base + tid;
        if (r < N) {
            s1[r] = p;
            s2[r] = q;
        }
    }
}

// ---------------- Kernel 2: coarse bucket histogram (src>>7) ----------------
__global__ __launch_bounds__(256) void gat_histb(
    const int* __restrict__ src, int* __restrict__ bucketCnt, int E, int NB) {
    __shared__ int lh[1024];
    int tid = threadIdx.x;
    for (int i = tid; i < 1024; i += 256) lh[i] = 0;
    __syncthreads();
    for (int i = blockIdx.x * 256 + tid; i < E; i += gridDim.x * 256)
        atomicAdd(&lh[src[i] >> NB_SHIFT], 1);
    __syncthreads();
    for (int b = tid; b < NB; b += 256)
        if (lh[b]) atomicAdd(&bucketCnt[b], lh[b]);
}

// ---------------- Kernel 3: scan bucketCnt (pairwise, <=1024 buckets) -------
__global__ __launch_bounds__(512) void gat_scan0(
    const int* __restrict__ bucketCnt, int* __restrict__ bucketBase,
    int* __restrict__ bucketCursor, int NB) {
    __shared__ int wsum[8];
    int tid = threadIdx.x, lane = tid & 63, wid = tid >> 6;
    int i0 = 2 * tid, i1 = 2 * tid + 1;
    int v0 = (i0 < NB) ? bucketCnt[i0] : 0;
    int v1 = (i1 < NB) ? bucketCnt[i1] : 0;
    int pv = v0 + v1;
    int x = pv;
#pragma unroll
    for (int off = 1; off < 64; off <<= 1) {
        int y = __shfl_up(x, off, 64);
        if (lane >= off) x += y;
    }
    if (lane == 63) wsum[wid] = x;
    __syncthreads();
    int add = 0;
    for (int w = 0; w < 8; ++w)
        if (w < wid) add += wsum[w];
    int ex = add + x - pv;
    if (i0 < NB) {
        bucketBase[i0] = ex;
        bucketCursor[i0] = ex;
    }
    if (i1 < NB) {
        bucketBase[i1] = ex + v0;
        bucketCursor[i1] = ex + v0;
    }
    if (i0 == NB - 1) bucketBase[NB] = ex + v0;
    if (i1 == NB - 1) bucketBase[NB] = ex + v0 + v1;
}

// ---------------- Kernel 4: coarse radix partition by src>>7 ----------------
__global__ __launch_bounds__(512) void gat_bin(
    const int* __restrict__ src, const int* __restrict__ dst,
    int* __restrict__ bucketCursor, int2* __restrict__ bucketData, int E) {
    __shared__ int hist[1024], excl[1024], gbase[1024], cur[1024];
    __shared__ int wsum[8];
    __shared__ int2 staged[BATCH];
    int tid = threadIdx.x, lane = tid & 63, wid = tid >> 6;
    int base = blockIdx.x * BATCH;
    int n = E - base;
    if (n > BATCH) n = BATCH;

    hist[tid] = 0;
    hist[tid + 512] = 0;
    __syncthreads();

    int se[8], de[8];
#pragma unroll
    for (int j = 0; j < 8; ++j) {
        int i = base + j * 512 + tid;
        se[j] = -1;
        de[j] = 0;
        if (i < E) {
            se[j] = src[i];
            de[j] = dst[i];
            atomicAdd(&hist[se[j] >> NB_SHIFT], 1);
        }
    }
    __syncthreads();
    // pairwise wave-shuffle exclusive scan of hist[1024]
    int v0 = hist[2 * tid], v1 = hist[2 * tid + 1];
    int pv = v0 + v1;
    int x = pv;
#pragma unroll
    for (int off = 1; off < 64; off <<= 1) {
        int y = __shfl_up(x, off, 64);
        if (lane >= off) x += y;
    }
    if (lane == 63) wsum[wid] = x;
    __syncthreads();
    int add = 0;
    for (int w = 0; w < 8; ++w)
        if (w < wid) add += wsum[w];
    int ex = add + x - pv;
    excl[2 * tid] = ex;
    excl[2 * tid + 1] = ex + v0;
    cur[2 * tid] = ex;
    cur[2 * tid + 1] = ex + v0;
    __syncthreads();
#pragma unroll
    for (int j = 0; j < 8; ++j) {
        if (se[j] >= 0) {
            int b = se[j] >> NB_SHIFT;
            int pos = atomicAdd(&cur[b], 1);
            staged[pos] = make_int2(se[j], de[j]);
        }
    }
    if (v0 > 0) gbase[2 * tid] = atomicAdd(&bucketCursor[2 * tid], v0);
    if (v1 > 0) gbase[2 * tid + 1] = atomicAdd(&bucketCursor[2 * tid + 1], v1);
    __syncthreads();
    for (int i = tid; i < n; i += 512) {
        int2 p = staged[i];
        int b = p.x >> NB_SHIFT;
        bucketData[gbase[b] + (i - excl[b])] = p;
    }
}

// ---------------- Kernel 5: bucket-local accumulate (LDS f32 atomics) -------
// One block per 128-node bucket. acc[128][68] fp32 in LDS; edges processed
// densely; no per-node loops, no shuffle reductions, no sortedDst.
__global__ __launch_bounds__(256) void gat_accum(
    const int* __restrict__ bucketBase, const int2* __restrict__ bucketData,
    const float* __restrict__ s1, const float* __restrict__ s2,
    const unsigned short* __restrict__ hb, float* __restrict__ out, int N) {
    __shared__ float accf[128 * ACC_STRIDE];  // 34816 B
    __shared__ float denom[128];
    __shared__ float s1l[128];
    __shared__ int stg_d[4][64];
    __shared__ float stg_a[4][64];
    __shared__ int stg_s[4][64];

    const int b = blockIdx.x;
    const int tid = threadIdx.x;
    const int lane = tid & 63, wave = tid >> 6;
    const int node0 = b << NB_SHIFT;
    const int beg = bucketBase[b];
    const int end = bucketBase[b + 1];

    // --- init: acc[r][:] = as * h[node]; denom[r] = as ---
    {
        int r = tid >> 1, half = tid & 1;
        int node = node0 + r;
        if (node < N) {
            float as = s1[node] + s2[node];
            as = (as >= 0.f) ? as : SLOPE * as;
            as = expf(as);
            if (half == 0) {
                denom[r] = as;
                s1l[r] = s1[node];
            }
            int fb = half * 32;
#pragma unroll
            for (int q = 0; q < 4; ++q) {
                uint4 hv = *(const uint4*)&hb[(size_t)node * F + fb + q * 8];
                float* ap = &accf[r * ACC_STRIDE + fb + q * 8];
                ap[0] = as * __uint_as_float(hv.x << 16);
                ap[1] = as * __uint_as_float(hv.x & 0xFFFF0000u);
                ap[2] = as * __uint_as_float(hv.y << 16);
                ap[3] = as * __uint_as_float(hv.y & 0xFFFF0000u);
                ap[4] = as * __uint_as_float(hv.z << 16);
                ap[5] = as * __uint_as_float(hv.z & 0xFFFF0000u);
                ap[6] = as * __uint_as_float(hv.w << 16);
                ap[7] = as * __uint_as_float(hv.w & 0xFFFF0000u);
            }
        } else {
            if (half == 0) {
                denom[r] = 1.f;
                s1l[r] = 0.f;
            }
            int fb = half * 32;
            for (int k = 0; k < 32; ++k) accf[r * ACC_STRIDE + fb + k] = 0.f;
        }
    }
    __syncthreads();

    const int fo = (lane & 7) * 8;   // feature octet
    const int sg = lane >> 3;        // edge slot within stage group

    // --- edge loop: each wave takes 64-edge chunks ---
    for (int c = beg + wave * 64; c < end; c += 256) {
        int i = c + lane;
        int sloc = 0, d = 0;
        float al = 0.f;
        if (i < end) {
            int2 p = bucketData[i];
            sloc = p.x & BMASK;
            d = p.y;
            float t = s1l[sloc] + s2[d];
            t = (t >= 0.f) ? t : SLOPE * t;
            al = expf(t);
            atomicAdd(&denom[sloc], al);
        }
        stg_d[wave][lane] = d;
        stg_a[wave][lane] = al;
        stg_s[wave][lane] = sloc;
        __builtin_amdgcn_wave_barrier();
        int nReal = end - c;
        if (nReal > 64) nReal = 64;
        int nIt = (nReal + 7) >> 3;
        for (int jj = 0; jj < nIt; ++jj) {
            int slot = jj * 8 + sg;
            if (slot < nReal) {
                int dj = stg_d[wave][slot];
                float aj = stg_a[wave][slot];
                int sj = stg_s[wave][slot];
                uint4 hv = *(const uint4*)&hb[(size_t)dj * F + fo];
                float* ap = &accf[sj * ACC_STRIDE + fo];
                atomicAdd(&ap[0], aj * __uint_as_float(hv.x << 16));
                atomicAdd(&ap[1], aj * __uint_as_float(hv.x & 0xFFFF0000u));
                atomicAdd(&ap[2], aj * __uint_as_float(hv.y << 16));
                atomicAdd(&ap[3], aj * __uint_as_float(hv.y & 0xFFFF0000u));
                atomicAdd(&ap[4], aj * __uint_as_float(hv.z << 16));
                atomicAdd(&ap[5], aj * __uint_as_float(hv.z & 0xFFFF0000u));
                atomicAdd(&ap[6], aj * __uint_as_float(hv.w << 16));
                atomicAdd(&ap[7], aj * __uint_as_float(hv.w & 0xFFFF0000u));
            }
        }
        __builtin_amdgcn_wave_barrier();
    }
    __syncthreads();

    // --- normalize + store ---
    {
        int r = tid >> 1, half = tid & 1;
        int node = node0 + r;
        if (node < N) {
            float inv = 1.0f / denom[r];
            int fb = half * 32;
#pragma unroll
            for (int q = 0; q < 8; ++q) {
                float4 v;
                float* ap = &accf[r * ACC_STRIDE + fb + q * 4];
                v.x = ap[0] * inv;
                v.y = ap[1] * inv;
                v.z = ap[2] * inv;
                v.w = ap[3] * inv;
                *(float4*)&out[(size_t)node * F + fb + q * 4] = v;
            }
        }
    }
}

extern "C" void kernel_launch(void* const* d_in, const int* in_sizes, int n_in,
                              void* d_out, int out_size, void* d_ws, size_t ws_size,
                              hipStream_t stream) {
    const float* X = (const float*)d_in[0];
    const int* edge = (const int*)d_in[1];
    const float* W = (const float*)d_in[2];
    const float* a = (const float*)d_in[3];

    int N = in_sizes[0] / F;
    int E = in_sizes[1] / 2;
    int NB = (N + BMASK) >> NB_SHIFT;  // 128-node buckets (<= 1024)

    const int* src = edge;
    const int* dst = edge + E;

    // ws: bucketData[E]int2 | hb[N*64]u16 | s1[N] | s2[N] |
    //     bucketCnt[1024] | bucketBase[1025] | bucketCursor[1024]
    int2* bucketData = (int2*)d_ws;
    unsigned short* hb = (unsigned short*)(bucketData + E);
    float* s1 = (float*)(hb + (size_t)N * F);
    float* s2 = s1 + N;
    int* bucketCnt = (int*)(s2 + N);
    int* bucketBase = bucketCnt + 1024;
    int* bucketCursor = bucketBase + 1025;

    float* out = (float*)d_out;

    hipMemsetAsync(bucketCnt, 0, 1024 * sizeof(int), stream);

    int gemmBlocks = (N + 127) / 128;
    gat_gemm<<<gemmBlocks, 256, 0, stream>>>(X, W, a, hb, s1, s2, N);

    gat_histb<<<256, 256, 0, stream>>>(src, bucketCnt, E, NB);
    gat_scan0<<<1, 512, 0, stream>>>(bucketCnt, bucketBase, bucketCursor, NB);

    int binBlocks = (E + BATCH - 1) / BATCH;
    gat_bin<<<binBlocks, 512, 0, stream>>>(src, dst, bucketCursor, bucketData, E);

    gat_accum<<<NB, 256, 0, stream>>>(bucketBase, bucketData, s1, s2, hb, out, N);
}

// Round 10
// 115.249 us; speedup vs baseline: 6.6254x; 6.6254x over previous
//
#include <hip/hip_runtime.h>
#include <hip/hip_bf16.h>

#define F 64
#define SLOPE 0.2f
#define NB_SHIFT 8     // 256 nodes per coarse bucket
#define BATCH 4096     // edges per gat_bin block

__device__ inline unsigned short f2bf(float f) {
    unsigned u = __float_as_uint(f);
    unsigned r = (u + 0x7FFFu + ((u >> 16) & 1u)) >> 16;
    return (unsigned short)r;
}

// ---------------- Kernel 1: h(bf16) = X @ W + fused s1/s2 -------------------
__global__ __launch_bounds__(256) void gat_gemm(
    const float* __restrict__ X, const float* __restrict__ W,
    const float* __restrict__ a, unsigned short* __restrict__ hb,
    float* __restrict__ s1, float* __restrict__ s2, int N) {
    __shared__ __align__(16) char smem[51200];
    float* XsT = (float*)smem;              // 64*132*4 = 33792 B
    float* Wsm = (float*)(smem + 33792);    // 64*68*4  = 17408 B

    const int tid = threadIdx.x;
    const int base = blockIdx.x * 128;

#pragma unroll
    for (int l = 0; l < 8; ++l) {
        int flat = l * 256 + tid;
        int rr = flat >> 4;
        int qc = flat & 15;
        float4 v = make_float4(0.f, 0.f, 0.f, 0.f);
        if (base + rr < N) v = *(const float4*)&X[(size_t)(base + rr) * F + qc * 4];
        XsT[(qc * 4 + 0) * 132 + rr] = v.x;
        XsT[(qc * 4 + 1) * 132 + rr] = v.y;
        XsT[(qc * 4 + 2) * 132 + rr] = v.z;
        XsT[(qc * 4 + 3) * 132 + rr] = v.w;
    }
#pragma unroll
    for (int l = 0; l < 4; ++l) {
        int flat = l * 256 + tid;
        int k = flat >> 4;
        int qc = flat & 15;
        float4 v = *(const float4*)&W[k * F + qc * 4];
        *(float4*)&Wsm[k * 68 + qc * 4] = v;
    }
    __syncthreads();

    const int r0 = (tid >> 4) * 8;
    const int c0 = (tid & 15) * 4;

    float4 acc[8];
#pragma unroll
    for (int i = 0; i < 8; ++i) acc[i] = make_float4(0.f, 0.f, 0.f, 0.f);

#pragma unroll 8
    for (int k = 0; k < F; ++k) {
        float4 xa = *(float4*)&XsT[k * 132 + r0];
        float4 xb = *(float4*)&XsT[k * 132 + r0 + 4];
        float4 wv = *(float4*)&Wsm[k * 68 + c0];
        float xs[8] = {xa.x, xa.y, xa.z, xa.w, xb.x, xb.y, xb.z, xb.w};
#pragma unroll
        for (int i = 0; i < 8; ++i) {
            acc[i].x = fmaf(xs[i], wv.x, acc[i].x);
            acc[i].y = fmaf(xs[i], wv.y, acc[i].y);
            acc[i].z = fmaf(xs[i], wv.z, acc[i].z);
            acc[i].w = fmaf(xs[i], wv.w, acc[i].w);
        }
    }

#pragma unroll
    for (int i = 0; i < 8; ++i) {
        int r = base + r0 + i;
        if (r < N) {
            ushort4 hv;
            hv.x = f2bf(acc[i].x);
            hv.y = f2bf(acc[i].y);
            hv.z = f2bf(acc[i].z);
            hv.w = f2bf(acc[i].w);
            *(ushort4*)&hb[(size_t)r * F + c0] = hv;
        }
    }

    float4 a1 = *(const float4*)&a[c0];
    float4 a2 = *(const float4*)&a[F + c0];
    __syncthreads();
    float2* red = (float2*)Wsm;            // [16][128] float2
    const int cg = tid & 15;
#pragma unroll
    for (int i = 0; i < 8; ++i) {
        float p = acc[i].x * a1.x + acc[i].y * a1.y + acc[i].z * a1.z + acc[i].w * a1.w;
        float q = acc[i].x * a2.x + acc[i].y * a2.y + acc[i].z * a2.z + acc[i].w * a2.w;
        red[cg * 128 + r0 + i] = make_float2(p, q);
    }
    __syncthreads();
    if (tid < 128) {
        float p = 0.f, q = 0.f;
#pragma unroll
        for (int g = 0; g < 16; ++g) {
            float2 t = red[g * 128 + tid];
            p += t.x;
            q += t.y;
        }
        int r = base + tid;
        if (r < N) {
            s1[r] = p;
            s2[r] = q;
        }
    }
}

// ---------------- Kernel 2: coarse bucket histogram only --------------------
__global__ __launch_bounds__(256) void gat_histb(
    const int* __restrict__ src, int* __restrict__ bucketCnt, int E, int NB) {
    __shared__ int lh[512];
    int tid = threadIdx.x;
    for (int i = tid; i < 512; i += 256) lh[i] = 0;
    __syncthreads();
    for (int i = blockIdx.x * 256 + tid; i < E; i += gridDim.x * 256)
        atomicAdd(&lh[src[i] >> NB_SHIFT], 1);
    __syncthreads();
    for (int b = tid; b < NB; b += 256)
        if (lh[b]) atomicAdd(&bucketCnt[b], lh[b]);
}

// ---------------- Kernel 3: scan bucketCnt -> bucketBase/bucketCursor -------
__global__ __launch_bounds__(512) void gat_scan0(
    const int* __restrict__ bucketCnt, int* __restrict__ bucketBase,
    int* __restrict__ bucketCursor, int* __restrict__ rowptrN, int NB) {
    __shared__ int wsum[8];
    int tid = threadIdx.x, lane = tid & 63, wid = tid >> 6;
    int v = (tid < NB) ? bucketCnt[tid] : 0;
    int x = v;
#pragma unroll
    for (int off = 1; off < 64; off <<= 1) {
        int y = __shfl_up(x, off, 64);
        if (lane >= off) x += y;
    }
    if (lane == 63) wsum[wid] = x;
    __syncthreads();
    int add = 0;
    for (int w = 0; w < 8; ++w)
        if (w < wid) add += wsum[w];
    int excl = add + x - v;
    if (tid < NB) {
        bucketBase[tid] = excl;
        bucketCursor[tid] = excl;
    }
    if (tid == NB - 1) {
        bucketBase[NB] = excl + v;   // == E
        rowptrN[0] = excl + v;       // rowptr[N] = E
    }
}

// ---------------- Kernel 4: coarse radix partition by src>>8 ----------------
__global__ __launch_bounds__(512) void gat_bin(
    const int* __restrict__ src, const int* __restrict__ dst,
    int* __restrict__ bucketCursor, int2* __restrict__ bucketData, int E) {
    __shared__ int hist[512], excl[512], gbase[512], cur[512];
    __shared__ int wsum[8];
    __shared__ int2 staged[BATCH];
    int tid = threadIdx.x, lane = tid & 63, wid = tid >> 6;
    int base = blockIdx.x * BATCH;
    int n = E - base;
    if (n > BATCH) n = BATCH;

    hist[tid] = 0;
    __syncthreads();

    int se[8], de[8];
#pragma unroll
    for (int j = 0; j < 8; ++j) {
        int i = base + j * 512 + tid;
        se[j] = -1;
        de[j] = 0;
        if (i < E) {
            se[j] = src[i];
            de[j] = dst[i];
            atomicAdd(&hist[se[j] >> NB_SHIFT], 1);
        }
    }
    __syncthreads();
    // wave-shuffle exclusive scan of hist[512]
    int v = hist[tid];
    int x = v;
#pragma unroll
    for (int off = 1; off < 64; off <<= 1) {
        int y = __shfl_up(x, off, 64);
        if (lane >= off) x += y;
    }
    if (lane == 63) wsum[wid] = x;
    __syncthreads();
    int add = 0;
    for (int w = 0; w < 8; ++w)
        if (w < wid) add += wsum[w];
    int ex = add + x - v;
    excl[tid] = ex;
    cur[tid] = ex;
    __syncthreads();
#pragma unroll
    for (int j = 0; j < 8; ++j) {
        if (se[j] >= 0) {
            int b = se[j] >> NB_SHIFT;
            int pos = atomicAdd(&cur[b], 1);
            staged[pos] = make_int2(se[j], de[j]);
        }
    }
    if (v > 0)
        gbase[tid] = atomicAdd(&bucketCursor[tid], v);
    __syncthreads();
    for (int i = tid; i < n; i += 512) {
        int2 p = staged[i];
        int b = p.x >> NB_SHIFT;
        bucketData[gbase[b] + (i - excl[b])] = p;
    }
}

// ---------------- Kernel 5: bucket-local CSR build (LDS atomics only) -------
__global__ __launch_bounds__(256) void gat_bucket(
    const int* __restrict__ bucketBase, const int2* __restrict__ bucketData,
    int* __restrict__ rowptr, int* __restrict__ sortedDst, int N) {
    __shared__ int cnt[256], cur[256];
    __shared__ int wsum[4];
    int b = blockIdx.x;
    int tid = threadIdx.x, lane = tid & 63, wid = tid >> 6;
    int beg = bucketBase[b];
    int end = bucketBase[b + 1];
    int node0 = b << NB_SHIFT;

    cnt[tid] = 0;
    __syncthreads();
    for (int i = beg + tid; i < end; i += 256)
        atomicAdd(&cnt[bucketData[i].x & 255], 1);
    __syncthreads();
    int v = cnt[tid];
    int x = v;
#pragma unroll
    for (int off = 1; off < 64; off <<= 1) {
        int y = __shfl_up(x, off, 64);
        if (lane >= off) x += y;
    }
    if (lane == 63) wsum[wid] = x;
    __syncthreads();
    int add = 0;
    for (int w = 0; w < 4; ++w)
        if (w < wid) add += wsum[w];
    int excl = add + x - v;
    int node = node0 + tid;
    if (node < N) rowptr[node] = beg + excl;
    cur[tid] = beg + excl;
    __syncthreads();
    for (int i = beg + tid; i < end; i += 256) {
        int2 p = bucketData[i];
        int pos = atomicAdd(&cur[p.x & 255], 1);
        sortedDst[pos] = p.y;
    }
}

// ---------------- Kernel 6: aggregate, 8 nodes/wave, 8-lane subgroup/node ---
// Each subgroup owns one node's full 64-feature row (8 bf16 per lane).
// All 8 lanes process each edge redundantly for alpha -> dsum identical on
// every lane: no cross-lane reduction, no LDS, no staging.
__global__ __launch_bounds__(256) void gat_aggregate(
    const int* __restrict__ rowptr,
    const int* __restrict__ sortedDst,
    const float* __restrict__ s1, const float* __restrict__ s2,
    const unsigned short* __restrict__ hb, float* __restrict__ out, int N) {
    int tid = threadIdx.x;
    int node = blockIdx.x * 32 + (tid >> 3);
    if (node >= N) return;
    const int fo = (tid & 7) * 8;    // feature octet owned by this lane

    int beg = rowptr[node];
    int end = rowptr[node + 1];
    float s1s = s1[node];
    float as = s1s + s2[node];
    as = (as >= 0.f) ? as : SLOPE * as;
    as = expf(as);

    float accA[8], accB[8];
    {
        uint4 hv = *(const uint4*)&hb[(size_t)node * F + fo];
        accA[0] = as * __uint_as_float(hv.x << 16);
        accA[1] = as * __uint_as_float(hv.x & 0xFFFF0000u);
        accA[2] = as * __uint_as_float(hv.y << 16);
        accA[3] = as * __uint_as_float(hv.y & 0xFFFF0000u);
        accA[4] = as * __uint_as_float(hv.z << 16);
        accA[5] = as * __uint_as_float(hv.z & 0xFFFF0000u);
        accA[6] = as * __uint_as_float(hv.w << 16);
        accA[7] = as * __uint_as_float(hv.w & 0xFFFF0000u);
    }
#pragma unroll
    for (int i = 0; i < 8; ++i) accB[i] = 0.f;

    float dsum = as;
    int e = beg;
    for (; e + 2 <= end; e += 2) {
        int d0 = sortedDst[e];
        int d1 = sortedDst[e + 1];
        float t0 = s1s + s2[d0];
        float t1 = s1s + s2[d1];
        t0 = (t0 >= 0.f) ? t0 : SLOPE * t0;
        t1 = (t1 >= 0.f) ? t1 : SLOPE * t1;
        float a0 = expf(t0);
        float a1 = expf(t1);
        dsum += a0 + a1;
        uint4 g0 = *(const uint4*)&hb[(size_t)d0 * F + fo];
        uint4 g1 = *(const uint4*)&hb[(size_t)d1 * F + fo];
        accA[0] = fmaf(a0, __uint_as_float(g0.x << 16), accA[0]);
        accA[1] = fmaf(a0, __uint_as_float(g0.x & 0xFFFF0000u), accA[1]);
        accA[2] = fmaf(a0, __uint_as_float(g0.y << 16), accA[2]);
        accA[3] = fmaf(a0, __uint_as_float(g0.y & 0xFFFF0000u), accA[3]);
        accA[4] = fmaf(a0, __uint_as_float(g0.z << 16), accA[4]);
        accA[5] = fmaf(a0, __uint_as_float(g0.z & 0xFFFF0000u), accA[5]);
        accA[6] = fmaf(a0, __uint_as_float(g0.w << 16), accA[6]);
        accA[7] = fmaf(a0, __uint_as_float(g0.w & 0xFFFF0000u), accA[7]);
        accB[0] = fmaf(a1, __uint_as_float(g1.x << 16), accB[0]);
        accB[1] = fmaf(a1, __uint_as_float(g1.x & 0xFFFF0000u), accB[1]);
        accB[2] = fmaf(a1, __uint_as_float(g1.y << 16), accB[2]);
        accB[3] = fmaf(a1, __uint_as_float(g1.y & 0xFFFF0000u), accB[3]);
        accB[4] = fmaf(a1, __uint_as_float(g1.z << 16), accB[4]);
        accB[5] = fmaf(a1, __uint_as_float(g1.z & 0xFFFF0000u), accB[5]);
        accB[6] = fmaf(a1, __uint_as_float(g1.w << 16), accB[6]);
        accB[7] = fmaf(a1, __uint_as_float(g1.w & 0xFFFF0000u), accB[7]);
    }
    if (e < end) {
        int d0 = sortedDst[e];
        float t0 = s1s + s2[d0];
        t0 = (t0 >= 0.f) ? t0 : SLOPE * t0;
        float a0 = expf(t0);
        dsum += a0;
        uint4 g0 = *(const uint4*)&hb[(size_t)d0 * F + fo];
        accA[0] = fmaf(a0, __uint_as_float(g0.x << 16), accA[0]);
        accA[1] = fmaf(a0, __uint_as_float(g0.x & 0xFFFF0000u), accA[1]);
        accA[2] = fmaf(a0, __uint_as_float(g0.y << 16), accA[2]);
        accA[3] = fmaf(a0, __uint_as_float(g0.y & 0xFFFF0000u), accA[3]);
        accA[4] = fmaf(a0, __uint_as_float(g0.z << 16), accA[4]);
        accA[5] = fmaf(a0, __uint_as_float(g0.z & 0xFFFF0000u), accA[5]);
        accA[6] = fmaf(a0, __uint_as_float(g0.w << 16), accA[6]);
        accA[7] = fmaf(a0, __uint_as_float(g0.w & 0xFFFF0000u), accA[7]);
    }

    float inv = 1.0f / dsum;
    float4 r0, r1;
    r0.x = (accA[0] + accB[0]) * inv;
    r0.y = (accA[1] + accB[1]) * inv;
    r0.z = (accA[2] + accB[2]) * inv;
    r0.w = (accA[3] + accB[3]) * inv;
    r1.x = (accA[4] + accB[4]) * inv;
    r1.y = (accA[5] + accB[5]) * inv;
    r1.z = (accA[6] + accB[6]) * inv;
    r1.w = (accA[7] + accB[7]) * inv;
    *(float4*)&out[(size_t)node * F + fo] = r0;
    *(float4*)&out[(size_t)node * F + fo + 4] = r1;
}

extern "C" void kernel_launch(void* const* d_in, const int* in_sizes, int n_in,
                              void* d_out, int out_size, void* d_ws, size_t ws_size,
                              hipStream_t stream) {
    const float* X = (const float*)d_in[0];
    const int* edge = (const int*)d_in[1];
    const float* W = (const float*)d_in[2];
    const float* a = (const float*)d_in[3];

    int N = in_sizes[0] / F;
    int E = in_sizes[1] / 2;
    int NB = (N + 255) >> NB_SHIFT;   // 256-node buckets (<= 512)

    const int* src = edge;
    const int* dst = edge + E;

    int2* bucketData = (int2*)d_ws;
    unsigned short* hb = (unsigned short*)(bucketData + E);
    float* s1 = (float*)(hb + (size_t)N * F);
    float* s2 = s1 + N;
    int* bucketCnt = (int*)(s2 + N);
    int* bucketBase = bucketCnt + 512;
    int* bucketCursor = bucketBase + 513;
    int* rowptr = bucketCursor + 512;
    int* sortedDst = rowptr + (N + 1);

    float* out = (float*)d_out;

    hipMemsetAsync(bucketCnt, 0, 512 * sizeof(int), stream);

    int gemmBlocks = (N + 127) / 128;
    gat_gemm<<<gemmBlocks, 256, 0, stream>>>(X, W, a, hb, s1, s2, N);

    gat_histb<<<256, 256, 0, stream>>>(src, bucketCnt, E, NB);
    gat_scan0<<<1, 512, 0, stream>>>(bucketCnt, bucketBase, bucketCursor,
                                     rowptr + N, NB);

    int binBlocks = (E + BATCH - 1) / BATCH;
    gat_bin<<<binBlocks, 512, 0, stream>>>(src, dst, bucketCursor, bucketData, E);

    gat_bucket<<<NB, 256, 0, stream>>>(bucketBase, bucketData, rowptr,
                                       sortedDst, N);

    int aggBlocks = (N + 31) / 32;
    gat_aggregate<<<aggBlocks, 256, 0, stream>>>(rowptr, sortedDst,
                                                 s1, s2, hb, out, N);
}

// Round 11
// 113.833 us; speedup vs baseline: 6.7078x; 1.0124x over previous
//
#include <hip/hip_runtime.h>
#include <hip/hip_bf16.h>

#define F 64
#define SLOPE 0.2f
#define NB_SHIFT 8     // 256 nodes per coarse bucket
#define BATCH 4096     // edges per gat_bin block
#define HIST_BLOCKS 256

__device__ inline unsigned short f2bf(float f) {
    unsigned u = __float_as_uint(f);
    unsigned r = (u + 0x7FFFu + ((u >> 16) & 1u)) >> 16;
    return (unsigned short)r;
}

// ---------------- Kernel 1: h(bf16) = X @ W + fused s1/s2 -------------------
__global__ __launch_bounds__(256) void gat_gemm(
    const float* __restrict__ X, const float* __restrict__ W,
    const float* __restrict__ a, unsigned short* __restrict__ hb,
    float* __restrict__ s1, float* __restrict__ s2, int N) {
    __shared__ __align__(16) char smem[51200];
    float* XsT = (float*)smem;              // 64*132*4 = 33792 B
    float* Wsm = (float*)(smem + 33792);    // 64*68*4  = 17408 B

    const int tid = threadIdx.x;
    const int base = blockIdx.x * 128;

#pragma unroll
    for (int l = 0; l < 8; ++l) {
        int flat = l * 256 + tid;
        int rr = flat >> 4;
        int qc = flat & 15;
        float4 v = make_float4(0.f, 0.f, 0.f, 0.f);
        if (base + rr < N) v = *(const float4*)&X[(size_t)(base + rr) * F + qc * 4];
        XsT[(qc * 4 + 0) * 132 + rr] = v.x;
        XsT[(qc * 4 + 1) * 132 + rr] = v.y;
        XsT[(qc * 4 + 2) * 132 + rr] = v.z;
        XsT[(qc * 4 + 3) * 132 + rr] = v.w;
    }
#pragma unroll
    for (int l = 0; l < 4; ++l) {
        int flat = l * 256 + tid;
        int k = flat >> 4;
        int qc = flat & 15;
        float4 v = *(const float4*)&W[k * F + qc * 4];
        *(float4*)&Wsm[k * 68 + qc * 4] = v;
    }
    __syncthreads();

    const int r0 = (tid >> 4) * 8;
    const int c0 = (tid & 15) * 4;

    float4 acc[8];
#pragma unroll
    for (int i = 0; i < 8; ++i) acc[i] = make_float4(0.f, 0.f, 0.f, 0.f);

#pragma unroll 8
    for (int k = 0; k < F; ++k) {
        float4 xa = *(float4*)&XsT[k * 132 + r0];
        float4 xb = *(float4*)&XsT[k * 132 + r0 + 4];
        float4 wv = *(float4*)&Wsm[k * 68 + c0];
        float xs[8] = {xa.x, xa.y, xa.z, xa.w, xb.x, xb.y, xb.z, xb.w};
#pragma unroll
        for (int i = 0; i < 8; ++i) {
            acc[i].x = fmaf(xs[i], wv.x, acc[i].x);
            acc[i].y = fmaf(xs[i], wv.y, acc[i].y);
            acc[i].z = fmaf(xs[i], wv.z, acc[i].z);
            acc[i].w = fmaf(xs[i], wv.w, acc[i].w);
        }
    }

#pragma unroll
    for (int i = 0; i < 8; ++i) {
        int r = base + r0 + i;
        if (r < N) {
            ushort4 hv;
            hv.x = f2bf(acc[i].x);
            hv.y = f2bf(acc[i].y);
            hv.z = f2bf(acc[i].z);
            hv.w = f2bf(acc[i].w);
            *(ushort4*)&hb[(size_t)r * F + c0] = hv;
        }
    }

    float4 a1 = *(const float4*)&a[c0];
    float4 a2 = *(const float4*)&a[F + c0];
    __syncthreads();
    float2* red = (float2*)Wsm;            // [16][128] float2
    const int cg = tid & 15;
#pragma unroll
    for (int i = 0; i < 8; ++i) {
        float p = acc[i].x * a1.x + acc[i].y * a1.y + acc[i].z * a1.z + acc[i].w * a1.w;
        float q = acc[i].x * a2.x + acc[i].y * a2.y + acc[i].z * a2.z + acc[i].w * a2.w;
        red[cg * 128 + r0 + i] = make_float2(p, q);
    }
    __syncthreads();
    if (tid < 128) {
        float p = 0.f, q = 0.f;
#pragma unroll
        for (int g = 0; g < 16; ++g) {
            float2 t = red[g * 128 + tid];
            p += t.x;
            q += t.y;
        }
        int r = base + tid;
        if (r < N) {
            s1[r] = p;
            s2[r] = q;
        }
    }
}

// ---------------- Kernel 2: bucket histogram, per-block partials ------------
// No global atomics, no pre-zeroed buffer: each block stores its full 512-entry
// LDS histogram to partialHist[block][512].
__global__ __launch_bounds__(256) void gat_histb(
    const int* __restrict__ src, int* __restrict__ partialHist, int E) {
    __shared__ int lh[512];
    int tid = threadIdx.x;
    for (int i = tid; i < 512; i += 256) lh[i] = 0;
    __syncthreads();
    for (int i = blockIdx.x * 256 + tid; i < E; i += gridDim.x * 256)
        atomicAdd(&lh[src[i] >> NB_SHIFT], 1);
    __syncthreads();
    for (int i = tid; i < 512; i += 256)
        partialHist[blockIdx.x * 512 + i] = lh[i];
}

// ---------------- Kernel 3: sum partials + scan -> bucketBase/Cursor --------
__global__ __launch_bounds__(512) void gat_scan0(
    const int* __restrict__ partialHist, int* __restrict__ bucketBase,
    int* __restrict__ bucketCursor, int* __restrict__ rowptrN, int NB) {
    __shared__ int wsum[8];
    int tid = threadIdx.x, lane = tid & 63, wid = tid >> 6;
    int v = 0;
    for (int p = 0; p < HIST_BLOCKS; ++p)
        v += partialHist[p * 512 + tid];   // zero for tid >= NB by construction
    int x = v;
#pragma unroll
    for (int off = 1; off < 64; off <<= 1) {
        int y = __shfl_up(x, off, 64);
        if (lane >= off) x += y;
    }
    if (lane == 63) wsum[wid] = x;
    __syncthreads();
    int add = 0;
    for (int w = 0; w < 8; ++w)
        if (w < wid) add += wsum[w];
    int excl = add + x - v;
    if (tid < NB) {
        bucketBase[tid] = excl;
        bucketCursor[tid] = excl;
    }
    if (tid == NB - 1) {
        bucketBase[NB] = excl + v;   // == E
        rowptrN[0] = excl + v;       // rowptr[N] = E
    }
}

// ---------------- Kernel 4: coarse radix partition by src>>8 ----------------
__global__ __launch_bounds__(512) void gat_bin(
    const int* __restrict__ src, const int* __restrict__ dst,
    int* __restrict__ bucketCursor, int2* __restrict__ bucketData, int E) {
    __shared__ int hist[512], excl[512], gbase[512], cur[512];
    __shared__ int wsum[8];
    __shared__ int2 staged[BATCH];
    int tid = threadIdx.x, lane = tid & 63, wid = tid >> 6;
    int base = blockIdx.x * BATCH;
    int n = E - base;
    if (n > BATCH) n = BATCH;

    hist[tid] = 0;
    __syncthreads();

    int se[8], de[8];
#pragma unroll
    for (int j = 0; j < 8; ++j) {
        int i = base + j * 512 + tid;
        se[j] = -1;
        de[j] = 0;
        if (i < E) {
            se[j] = src[i];
            de[j] = dst[i];
            atomicAdd(&hist[se[j] >> NB_SHIFT], 1);
        }
    }
    __syncthreads();
    int v = hist[tid];
    int x = v;
#pragma unroll
    for (int off = 1; off < 64; off <<= 1) {
        int y = __shfl_up(x, off, 64);
        if (lane >= off) x += y;
    }
    if (lane == 63) wsum[wid] = x;
    __syncthreads();
    int add = 0;
    for (int w = 0; w < 8; ++w)
        if (w < wid) add += wsum[w];
    int ex = add + x - v;
    excl[tid] = ex;
    cur[tid] = ex;
    __syncthreads();
#pragma unroll
    for (int j = 0; j < 8; ++j) {
        if (se[j] >= 0) {
            int b = se[j] >> NB_SHIFT;
            int pos = atomicAdd(&cur[b], 1);
            staged[pos] = make_int2(se[j], de[j]);
        }
    }
    if (v > 0)
        gbase[tid] = atomicAdd(&bucketCursor[tid], v);
    __syncthreads();
    for (int i = tid; i < n; i += 512) {
        int2 p = staged[i];
        int b = p.x >> NB_SHIFT;
        bucketData[gbase[b] + (i - excl[b])] = p;
    }
}

// ---------------- Kernel 5: bucket-local CSR build (LDS atomics only) -------
__global__ __launch_bounds__(256) void gat_bucket(
    const int* __restrict__ bucketBase, const int2* __restrict__ bucketData,
    int* __restrict__ rowptr, int* __restrict__ sortedDst, int N) {
    __shared__ int cnt[256], cur[256];
    __shared__ int wsum[4];
    int b = blockIdx.x;
    int tid = threadIdx.x, lane = tid & 63, wid = tid >> 6;
    int beg = bucketBase[b];
    int end = bucketBase[b + 1];
    int node0 = b << NB_SHIFT;

    cnt[tid] = 0;
    __syncthreads();
    for (int i = beg + tid; i < end; i += 256)
        atomicAdd(&cnt[bucketData[i].x & 255], 1);
    __syncthreads();
    int v = cnt[tid];
    int x = v;
#pragma unroll
    for (int off = 1; off < 64; off <<= 1) {
        int y = __shfl_up(x, off, 64);
        if (lane >= off) x += y;
    }
    if (lane == 63) wsum[wid] = x;
    __syncthreads();
    int add = 0;
    for (int w = 0; w < 4; ++w)
        if (w < wid) add += wsum[w];
    int excl = add + x - v;
    int node = node0 + tid;
    if (node < N) rowptr[node] = beg + excl;
    cur[tid] = beg + excl;
    __syncthreads();
    for (int i = beg + tid; i < end; i += 256) {
        int2 p = bucketData[i];
        int pos = atomicAdd(&cur[p.x & 255], 1);
        sortedDst[pos] = p.y;
    }
}

// ---------------- Kernel 6: aggregate, 8 nodes/wave, 8-lane subgroup/node ---
__global__ __launch_bounds__(256) void gat_aggregate(
    const int* __restrict__ rowptr,
    const int* __restrict__ sortedDst,
    const float* __restrict__ s1, const float* __restrict__ s2,
    const unsigned short* __restrict__ hb, float* __restrict__ out, int N) {
    int tid = threadIdx.x;
    int node = blockIdx.x * 32 + (tid >> 3);
    if (node >= N) return;
    const int fo = (tid & 7) * 8;    // feature octet owned by this lane

    int beg = rowptr[node];
    int end = rowptr[node + 1];
    float s1s = s1[node];
    float as = s1s + s2[node];
    as = (as >= 0.f) ? as : SLOPE * as;
    as = expf(as);

    float accA[8], accB[8];
    {
        uint4 hv = *(const uint4*)&hb[(size_t)node * F + fo];
        accA[0] = as * __uint_as_float(hv.x << 16);
        accA[1] = as * __uint_as_float(hv.x & 0xFFFF0000u);
        accA[2] = as * __uint_as_float(hv.y << 16);
        accA[3] = as * __uint_as_float(hv.y & 0xFFFF0000u);
        accA[4] = as * __uint_as_float(hv.z << 16);
        accA[5] = as * __uint_as_float(hv.z & 0xFFFF0000u);
        accA[6] = as * __uint_as_float(hv.w << 16);
        accA[7] = as * __uint_as_float(hv.w & 0xFFFF0000u);
    }
#pragma unroll
    for (int i = 0; i < 8; ++i) accB[i] = 0.f;

    float dsum = as;
    int e = beg;
    for (; e + 2 <= end; e += 2) {
        int d0 = sortedDst[e];
        int d1 = sortedDst[e + 1];
        float t0 = s1s + s2[d0];
        float t1 = s1s + s2[d1];
        t0 = (t0 >= 0.f) ? t0 : SLOPE * t0;
        t1 = (t1 >= 0.f) ? t1 : SLOPE * t1;
        float a0 = expf(t0);
        float a1 = expf(t1);
        dsum += a0 + a1;
        uint4 g0 = *(const uint4*)&hb[(size_t)d0 * F + fo];
        uint4 g1 = *(const uint4*)&hb[(size_t)d1 * F + fo];
        accA[0] = fmaf(a0, __uint_as_float(g0.x << 16), accA[0]);
        accA[1] = fmaf(a0, __uint_as_float(g0.x & 0xFFFF0000u), accA[1]);
        accA[2] = fmaf(a0, __uint_as_float(g0.y << 16), accA[2]);
        accA[3] = fmaf(a0, __uint_as_float(g0.y & 0xFFFF0000u), accA[3]);
        accA[4] = fmaf(a0, __uint_as_float(g0.z << 16), accA[4]);
        accA[5] = fmaf(a0, __uint_as_float(g0.z & 0xFFFF0000u), accA[5]);
        accA[6] = fmaf(a0, __uint_as_float(g0.w << 16), accA[6]);
        accA[7] = fmaf(a0, __uint_as_float(g0.w & 0xFFFF0000u), accA[7]);
        accB[0] = fmaf(a1, __uint_as_float(g1.x << 16), accB[0]);
        accB[1] = fmaf(a1, __uint_as_float(g1.x & 0xFFFF0000u), accB[1]);
        accB[2] = fmaf(a1, __uint_as_float(g1.y << 16), accB[2]);
        accB[3] = fmaf(a1, __uint_as_float(g1.y & 0xFFFF0000u), accB[3]);
        accB[4] = fmaf(a1, __uint_as_float(g1.z << 16), accB[4]);
        accB[5] = fmaf(a1, __uint_as_float(g1.z & 0xFFFF0000u), accB[5]);
        accB[6] = fmaf(a1, __uint_as_float(g1.w << 16), accB[6]);
        accB[7] = fmaf(a1, __uint_as_float(g1.w & 0xFFFF0000u), accB[7]);
    }
    if (e < end) {
        int d0 = sortedDst[e];
        float t0 = s1s + s2[d0];
        t0 = (t0 >= 0.f) ? t0 : SLOPE * t0;
        float a0 = expf(t0);
        dsum += a0;
        uint4 g0 = *(const uint4*)&hb[(size_t)d0 * F + fo];
        accA[0] = fmaf(a0, __uint_as_float(g0.x << 16), accA[0]);
        accA[1] = fmaf(a0, __uint_as_float(g0.x & 0xFFFF0000u), accA[1]);
        accA[2] = fmaf(a0, __uint_as_float(g0.y << 16), accA[2]);
        accA[3] = fmaf(a0, __uint_as_float(g0.y & 0xFFFF0000u), accA[3]);
        accA[4] = fmaf(a0, __uint_as_float(g0.z << 16), accA[4]);
        accA[5] = fmaf(a0, __uint_as_float(g0.z & 0xFFFF0000u), accA[5]);
        accA[6] = fmaf(a0, __uint_as_float(g0.w << 16), accA[6]);
        accA[7] = fmaf(a0, __uint_as_float(g0.w & 0xFFFF0000u), accA[7]);
    }

    float inv = 1.0f / dsum;
    float4 r0, r1;
    r0.x = (accA[0] + accB[0]) * inv;
    r0.y = (accA[1] + accB[1]) * inv;
    r0.z = (accA[2] + accB[2]) * inv;
    r0.w = (accA[3] + accB[3]) * inv;
    r1.x = (accA[4] + accB[4]) * inv;
    r1.y = (accA[5] + accB[5]) * inv;
    r1.z = (accA[6] + accB[6]) * inv;
    r1.w = (accA[7] + accB[7]) * inv;
    *(float4*)&out[(size_t)node * F + fo] = r0;
    *(float4*)&out[(size_t)node * F + fo + 4] = r1;
}

extern "C" void kernel_launch(void* const* d_in, const int* in_sizes, int n_in,
                              void* d_out, int out_size, void* d_ws, size_t ws_size,
                              hipStream_t stream) {
    const float* X = (const float*)d_in[0];
    const int* edge = (const int*)d_in[1];
    const float* W = (const float*)d_in[2];
    const float* a = (const float*)d_in[3];

    int N = in_sizes[0] / F;
    int E = in_sizes[1] / 2;
    int NB = (N + 255) >> NB_SHIFT;   // 256-node buckets (<= 512)

    const int* src = edge;
    const int* dst = edge + E;

    // ws: bucketData[E]int2 | hb[N*64]u16 | s1[N] | s2[N] |
    //     partialHist[256*512] | bucketBase[513] | bucketCursor[512] |
    //     rowptr[N+1] | sortedDst[E]
    int2* bucketData = (int2*)d_ws;
    unsigned short* hb = (unsigned short*)(bucketData + E);
    float* s1 = (float*)(hb + (size_t)N * F);
    float* s2 = s1 + N;
    int* partialHist = (int*)(s2 + N);
    int* bucketBase = partialHist + HIST_BLOCKS * 512;
    int* bucketCursor = bucketBase + 513;
    int* rowptr = bucketCursor + 512;
    int* sortedDst = rowptr + (N + 1);

    float* out = (float*)d_out;

    int gemmBlocks = (N + 127) / 128;
    gat_gemm<<<gemmBlocks, 256, 0, stream>>>(X, W, a, hb, s1, s2, N);

    gat_histb<<<HIST_BLOCKS, 256, 0, stream>>>(src, partialHist, E);
    gat_scan0<<<1, 512, 0, stream>>>(partialHist, bucketBase, bucketCursor,
                                     rowptr + N, NB);

    int binBlocks = (E + BATCH - 1) / BATCH;
    gat_bin<<<binBlocks, 512, 0, stream>>>(src, dst, bucketCursor, bucketData, E);

    gat_bucket<<<NB, 256, 0, stream>>>(bucketBase, bucketData, rowptr,
                                       sortedDst, N);

    int aggBlocks = (N + 31) / 32;
    gat_aggregate<<<aggBlocks, 256, 0, stream>>>(rowptr, sortedDst,
                                                 s1, s2, hb, out, N);
}

// Round 12
// 105.854 us; speedup vs baseline: 7.2134x; 1.0754x over previous
//
#include <hip/hip_runtime.h>
#include <hip/hip_bf16.h>

#define F 64
#define SLOPE 0.2f
#define NB_SHIFT 8     // 256 nodes per coarse bucket
#define BATCH 4096     // edges per gat_bin block
#define HIST_BLOCKS 128

__device__ inline unsigned short f2bf(float f) {
    unsigned u = __float_as_uint(f);
    unsigned r = (u + 0x7FFFu + ((u >> 16) & 1u)) >> 16;
    return (unsigned short)r;
}

// ---------------- Kernel 1: fused [h(bf16) = X @ W + s1/s2] ∥ [bucket hist] -
// Blocks [0, gemmBlocks): GEMM. Blocks [gemmBlocks, +HIST_BLOCKS): histogram
// partials (no global atomics, no pre-zeroed buffer).
__global__ __launch_bounds__(256) void gat_gemm_hist(
    const float* __restrict__ X, const float* __restrict__ W,
    const float* __restrict__ a, unsigned short* __restrict__ hb,
    float* __restrict__ s1, float* __restrict__ s2, int N,
    const int* __restrict__ src, int* __restrict__ partialHist, int E,
    int gemmBlocks) {
    __shared__ __align__(16) char smem[51200];
    const int tid = threadIdx.x;

    if ((int)blockIdx.x >= gemmBlocks) {
        // ---- histogram part ----
        int hbid = blockIdx.x - gemmBlocks;
        int* lh = (int*)smem;
        for (int i = tid; i < 512; i += 256) lh[i] = 0;
        __syncthreads();
        for (int i = hbid * 256 + tid; i < E; i += HIST_BLOCKS * 256)
            atomicAdd(&lh[src[i] >> NB_SHIFT], 1);
        __syncthreads();
        for (int i = tid; i < 512; i += 256)
            partialHist[hbid * 512 + i] = lh[i];
        return;
    }

    // ---- GEMM part ----
    float* XsT = (float*)smem;              // 64*132*4 = 33792 B
    float* Wsm = (float*)(smem + 33792);    // 64*68*4  = 17408 B
    const int base = blockIdx.x * 128;

#pragma unroll
    for (int l = 0; l < 8; ++l) {
        int flat = l * 256 + tid;
        int rr = flat >> 4;
        int qc = flat & 15;
        float4 v = make_float4(0.f, 0.f, 0.f, 0.f);
        if (base + rr < N) v = *(const float4*)&X[(size_t)(base + rr) * F + qc * 4];
        XsT[(qc * 4 + 0) * 132 + rr] = v.x;
        XsT[(qc * 4 + 1) * 132 + rr] = v.y;
        XsT[(qc * 4 + 2) * 132 + rr] = v.z;
        XsT[(qc * 4 + 3) * 132 + rr] = v.w;
    }
#pragma unroll
    for (int l = 0; l < 4; ++l) {
        int flat = l * 256 + tid;
        int k = flat >> 4;
        int qc = flat & 15;
        float4 v = *(const float4*)&W[k * F + qc * 4];
        *(float4*)&Wsm[k * 68 + qc * 4] = v;
    }
    __syncthreads();

    const int r0 = (tid >> 4) * 8;
    const int c0 = (tid & 15) * 4;

    float4 acc[8];
#pragma unroll
    for (int i = 0; i < 8; ++i) acc[i] = make_float4(0.f, 0.f, 0.f, 0.f);

#pragma unroll 8
    for (int k = 0; k < F; ++k) {
        float4 xa = *(float4*)&XsT[k * 132 + r0];
        float4 xb = *(float4*)&XsT[k * 132 + r0 + 4];
        float4 wv = *(float4*)&Wsm[k * 68 + c0];
        float xs[8] = {xa.x, xa.y, xa.z, xa.w, xb.x, xb.y, xb.z, xb.w};
#pragma unroll
        for (int i = 0; i < 8; ++i) {
            acc[i].x = fmaf(xs[i], wv.x, acc[i].x);
            acc[i].y = fmaf(xs[i], wv.y, acc[i].y);
            acc[i].z = fmaf(xs[i], wv.z, acc[i].z);
            acc[i].w = fmaf(xs[i], wv.w, acc[i].w);
        }
    }

#pragma unroll
    for (int i = 0; i < 8; ++i) {
        int r = base + r0 + i;
        if (r < N) {
            ushort4 hv;
            hv.x = f2bf(acc[i].x);
            hv.y = f2bf(acc[i].y);
            hv.z = f2bf(acc[i].z);
            hv.w = f2bf(acc[i].w);
            *(ushort4*)&hb[(size_t)r * F + c0] = hv;
        }
    }

    float4 a1 = *(const float4*)&a[c0];
    float4 a2 = *(const float4*)&a[F + c0];
    __syncthreads();
    float2* red = (float2*)Wsm;            // [16][128] float2
    const int cg = tid & 15;
#pragma unroll
    for (int i = 0; i < 8; ++i) {
        float p = acc[i].x * a1.x + acc[i].y * a1.y + acc[i].z * a1.z + acc[i].w * a1.w;
        float q = acc[i].x * a2.x + acc[i].y * a2.y + acc[i].z * a2.z + acc[i].w * a2.w;
        red[cg * 128 + r0 + i] = make_float2(p, q);
    }
    __syncthreads();
    if (tid < 128) {
        float p = 0.f, q = 0.f;
#pragma unroll
        for (int g = 0; g < 16; ++g) {
            float2 t = red[g * 128 + tid];
            p += t.x;
            q += t.y;
        }
        int r = base + tid;
        if (r < N) {
            s1[r] = p;
            s2[r] = q;
        }
    }
}

// ---------------- Kernel 2: sum partials + scan -> bucketBase/Cursor --------
__global__ __launch_bounds__(512) void gat_scan0(
    const int* __restrict__ partialHist, int* __restrict__ bucketBase,
    int* __restrict__ bucketCursor, int* __restrict__ rowptrN, int NB) {
    __shared__ int wsum[8];
    int tid = threadIdx.x, lane = tid & 63, wid = tid >> 6;
    int v = 0;
    for (int p = 0; p < HIST_BLOCKS; ++p)
        v += partialHist[p * 512 + tid];
    int x = v;
#pragma unroll
    for (int off = 1; off < 64; off <<= 1) {
        int y = __shfl_up(x, off, 64);
        if (lane >= off) x += y;
    }
    if (lane == 63) wsum[wid] = x;
    __syncthreads();
    int add = 0;
    for (int w = 0; w < 8; ++w)
        if (w < wid) add += wsum[w];
    int excl = add + x - v;
    if (tid < NB) {
        bucketBase[tid] = excl;
        bucketCursor[tid] = excl;
    }
    if (tid == NB - 1) {
        bucketBase[NB] = excl + v;   // == E
        rowptrN[0] = excl + v;       // rowptr[N] = E
    }
}

// ---------------- Kernel 3: coarse radix partition by src>>8, packed out ----
// bucketData element: (src & 255) << 24 | dst   (dst < 2^24)
__global__ __launch_bounds__(512) void gat_bin(
    const int* __restrict__ src, const int* __restrict__ dst,
    int* __restrict__ bucketCursor, unsigned* __restrict__ bucketData, int E) {
    __shared__ int hist[512], excl[512], gbase[512], cur[512];
    __shared__ int wsum[8];
    __shared__ int2 staged[BATCH];
    int tid = threadIdx.x, lane = tid & 63, wid = tid >> 6;
    int base = blockIdx.x * BATCH;
    int n = E - base;
    if (n > BATCH) n = BATCH;

    hist[tid] = 0;
    __syncthreads();

    int se[8], de[8];
#pragma unroll
    for (int j = 0; j < 8; ++j) {
        int i = base + j * 512 + tid;
        se[j] = -1;
        de[j] = 0;
        if (i < E) {
            se[j] = src[i];
            de[j] = dst[i];
            atomicAdd(&hist[se[j] >> NB_SHIFT], 1);
        }
    }
    __syncthreads();
    int v = hist[tid];
    int x = v;
#pragma unroll
    for (int off = 1; off < 64; off <<= 1) {
        int y = __shfl_up(x, off, 64);
        if (lane >= off) x += y;
    }
    if (lane == 63) wsum[wid] = x;
    __syncthreads();
    int add = 0;
    for (int w = 0; w < 8; ++w)
        if (w < wid) add += wsum[w];
    int ex = add + x - v;
    excl[tid] = ex;
    cur[tid] = ex;
    __syncthreads();
#pragma unroll
    for (int j = 0; j < 8; ++j) {
        if (se[j] >= 0) {
            int b = se[j] >> NB_SHIFT;
            int pos = atomicAdd(&cur[b], 1);
            staged[pos] = make_int2(se[j], de[j]);
        }
    }
    if (v > 0)
        gbase[tid] = atomicAdd(&bucketCursor[tid], v);
    __syncthreads();
    for (int i = tid; i < n; i += 512) {
        int2 p = staged[i];
        int b = p.x >> NB_SHIFT;
        bucketData[gbase[b] + (i - excl[b])] =
            ((unsigned)(p.x & 255) << 24) | (unsigned)p.y;
    }
}

// ---------------- Kernel 4: bucket-local CSR build (LDS atomics only) -------
__global__ __launch_bounds__(256) void gat_bucket(
    const int* __restrict__ bucketBase, const unsigned* __restrict__ bucketData,
    int* __restrict__ rowptr, int* __restrict__ sortedDst, int N) {
    __shared__ int cnt[256], cur[256];
    __shared__ int wsum[4];
    int b = blockIdx.x;
    int tid = threadIdx.x, lane = tid & 63, wid = tid >> 6;
    int beg = bucketBase[b];
    int end = bucketBase[b + 1];
    int node0 = b << NB_SHIFT;

    cnt[tid] = 0;
    __syncthreads();
    for (int i = beg + tid; i < end; i += 256)
        atomicAdd(&cnt[bucketData[i] >> 24], 1);
    __syncthreads();
    int v = cnt[tid];
    int x = v;
#pragma unroll
    for (int off = 1; off < 64; off <<= 1) {
        int y = __shfl_up(x, off, 64);
        if (lane >= off) x += y;
    }
    if (lane == 63) wsum[wid] = x;
    __syncthreads();
    int add = 0;
    for (int w = 0; w < 4; ++w)
        if (w < wid) add += wsum[w];
    int excl = add + x - v;
    int node = node0 + tid;
    if (node < N) rowptr[node] = beg + excl;
    cur[tid] = beg + excl;
    __syncthreads();
    for (int i = beg + tid; i < end; i += 256) {
        unsigned w = bucketData[i];
        int pos = atomicAdd(&cur[w >> 24], 1);
        sortedDst[pos] = (int)(w & 0xFFFFFFu);
    }
}

// ---------------- Kernel 5: aggregate, 8 nodes/wave, 8-lane subgroup/node ---
__global__ __launch_bounds__(256) void gat_aggregate(
    const int* __restrict__ rowptr,
    const int* __restrict__ sortedDst,
    const float* __restrict__ s1, const float* __restrict__ s2,
    const unsigned short* __restrict__ hb, float* __restrict__ out, int N) {
    int tid = threadIdx.x;
    int node = blockIdx.x * 32 + (tid >> 3);
    if (node >= N) return;
    const int fo = (tid & 7) * 8;    // feature octet owned by this lane

    int beg = rowptr[node];
    int end = rowptr[node + 1];
    float s1s = s1[node];
    float as = s1s + s2[node];
    as = (as >= 0.f) ? as : SLOPE * as;
    as = expf(as);

    float accA[8], accB[8];
    {
        uint4 hv = *(const uint4*)&hb[(size_t)node * F + fo];
        accA[0] = as * __uint_as_float(hv.x << 16);
        accA[1] = as * __uint_as_float(hv.x & 0xFFFF0000u);
        accA[2] = as * __uint_as_float(hv.y << 16);
        accA[3] = as * __uint_as_float(hv.y & 0xFFFF0000u);
        accA[4] = as * __uint_as_float(hv.z << 16);
        accA[5] = as * __uint_as_float(hv.z & 0xFFFF0000u);
        accA[6] = as * __uint_as_float(hv.w << 16);
        accA[7] = as * __uint_as_float(hv.w & 0xFFFF0000u);
    }
#pragma unroll
    for (int i = 0; i < 8; ++i) accB[i] = 0.f;

    float dsum = as;
    int e = beg;
    for (; e + 2 <= end; e += 2) {
        int d0 = sortedDst[e];
        int d1 = sortedDst[e + 1];
        float t0 = s1s + s2[d0];
        float t1 = s1s + s2[d1];
        t0 = (t0 >= 0.f) ? t0 : SLOPE * t0;
        t1 = (t1 >= 0.f) ? t1 : SLOPE * t1;
        float a0 = expf(t0);
        float a1 = expf(t1);
        dsum += a0 + a1;
        uint4 g0 = *(const uint4*)&hb[(size_t)d0 * F + fo];
        uint4 g1 = *(const uint4*)&hb[(size_t)d1 * F + fo];
        accA[0] = fmaf(a0, __uint_as_float(g0.x << 16), accA[0]);
        accA[1] = fmaf(a0, __uint_as_float(g0.x & 0xFFFF0000u), accA[1]);
        accA[2] = fmaf(a0, __uint_as_float(g0.y << 16), accA[2]);
        accA[3] = fmaf(a0, __uint_as_float(g0.y & 0xFFFF0000u), accA[3]);
        accA[4] = fmaf(a0, __uint_as_float(g0.z << 16), accA[4]);
        accA[5] = fmaf(a0, __uint_as_float(g0.z & 0xFFFF0000u), accA[5]);
        accA[6] = fmaf(a0, __uint_as_float(g0.w << 16), accA[6]);
        accA[7] = fmaf(a0, __uint_as_float(g0.w & 0xFFFF0000u), accA[7]);
        accB[0] = fmaf(a1, __uint_as_float(g1.x << 16), accB[0]);
        accB[1] = fmaf(a1, __uint_as_float(g1.x & 0xFFFF0000u), accB[1]);
        accB[2] = fmaf(a1, __uint_as_float(g1.y << 16), accB[2]);
        accB[3] = fmaf(a1, __uint_as_float(g1.y & 0xFFFF0000u), accB[3]);
        accB[4] = fmaf(a1, __uint_as_float(g1.z << 16), accB[4]);
        accB[5] = fmaf(a1, __uint_as_float(g1.z & 0xFFFF0000u), accB[5]);
        accB[6] = fmaf(a1, __uint_as_float(g1.w << 16), accB[6]);
        accB[7] = fmaf(a1, __uint_as_float(g1.w & 0xFFFF0000u), accB[7]);
    }
    if (e < end) {
        int d0 = sortedDst[e];
        float t0 = s1s + s2[d0];
        t0 = (t0 >= 0.f) ? t0 : SLOPE * t0;
        float a0 = expf(t0);
        dsum += a0;
        uint4 g0 = *(const uint4*)&hb[(size_t)d0 * F + fo];
        accA[0] = fmaf(a0, __uint_as_float(g0.x << 16), accA[0]);
        accA[1] = fmaf(a0, __uint_as_float(g0.x & 0xFFFF0000u), accA[1]);
        accA[2] = fmaf(a0, __uint_as_float(g0.y << 16), accA[2]);
        accA[3] = fmaf(a0, __uint_as_float(g0.y & 0xFFFF0000u), accA[3]);
        accA[4] = fmaf(a0, __uint_as_float(g0.z << 16), accA[4]);
        accA[5] = fmaf(a0, __uint_as_float(g0.z & 0xFFFF0000u), accA[5]);
        accA[6] = fmaf(a0, __uint_as_float(g0.w << 16), accA[6]);
        accA[7] = fmaf(a0, __uint_as_float(g0.w & 0xFFFF0000u), accA[7]);
    }

    float inv = 1.0f / dsum;
    float4 r0, r1;
    r0.x = (accA[0] + accB[0]) * inv;
    r0.y = (accA[1] + accB[1]) * inv;
    r0.z = (accA[2] + accB[2]) * inv;
    r0.w = (accA[3] + accB[3]) * inv;
    r1.x = (accA[4] + accB[4]) * inv;
    r1.y = (accA[5] + accB[5]) * inv;
    r1.z = (accA[6] + accB[6]) * inv;
    r1.w = (accA[7] + accB[7]) * inv;
    *(float4*)&out[(size_t)node * F + fo] = r0;
    *(float4*)&out[(size_t)node * F + fo + 4] = r1;
}

extern "C" void kernel_launch(void* const* d_in, const int* in_sizes, int n_in,
                              void* d_out, int out_size, void* d_ws, size_t ws_size,
                              hipStream_t stream) {
    const float* X = (const float*)d_in[0];
    const int* edge = (const int*)d_in[1];
    const float* W = (const float*)d_in[2];
    const float* a = (const float*)d_in[3];

    int N = in_sizes[0] / F;
    int E = in_sizes[1] / 2;
    int NB = (N + 255) >> NB_SHIFT;   // 256-node buckets (<= 512)

    const int* src = edge;
    const int* dst = edge + E;

    // ws: bucketData[E]u32 | hb[N*64]u16 | s1[N] | s2[N] |
    //     partialHist[128*512] | bucketBase[513] | bucketCursor[512] |
    //     rowptr[N+1] | sortedDst[E]
    unsigned* bucketData = (unsigned*)d_ws;
    unsigned short* hb = (unsigned short*)(bucketData + E);
    float* s1 = (float*)(hb + (size_t)N * F);
    float* s2 = s1 + N;
    int* partialHist = (int*)(s2 + N);
    int* bucketBase = partialHist + HIST_BLOCKS * 512;
    int* bucketCursor = bucketBase + 513;
    int* rowptr = bucketCursor + 512;
    int* sortedDst = rowptr + (N + 1);

    float* out = (float*)d_out;

    int gemmBlocks = (N + 127) / 128;
    gat_gemm_hist<<<gemmBlocks + HIST_BLOCKS, 256, 0, stream>>>(
        X, W, a, hb, s1, s2, N, src, partialHist, E, gemmBlocks);

    gat_scan0<<<1, 512, 0, stream>>>(partialHist, bucketBase, bucketCursor,
                                     rowptr + N, NB);

    int binBlocks = (E + BATCH - 1) / BATCH;
    gat_bin<<<binBlocks, 512, 0, stream>>>(src, dst, bucketCursor, bucketData, E);

    gat_bucket<<<NB, 256, 0, stream>>>(bucketBase, bucketData, rowptr,
                                       sortedDst, N);

    int aggBlocks = (N + 31) / 32;
    gat_aggregate<<<aggBlocks, 256, 0, stream>>>(rowptr, sortedDst,
                                                 s1, s2, hb, out, N);
}